// Round 5
// baseline (1376.580 us; speedup 1.0000x reference)
//
#include <hip/hip_runtime.h>

// LowRankKVCache: out = X @ P where P = Vt^T Vt, Vt = top-64 eigenvectors of
// X^T X. 64 independent 2048x128 fp32 matrices (B*H = 4*16).
//
// Round 5: (a) register-resident brick-wall one-sided Jacobi: columns live in
// registers; even steps are LDS-free, odd steps exchange one column per
// neighbor pair through LDS with redundant (bit-identical) rotation compute
// on both sides -- DS traffic halved vs round 4 and dots on carried norms
// removed. (b) select/gemm1/gemm2 replaced by projector P = sum v v^T / |v|^2
// (pmat_k) and a single GEMM out = X @ P (recon_k) -- kills the 64 MB W
// round-trip.
//
// ws layout (bytes):
//   [0, 4M)        G      (64 x 128x128 f32)   -- dead after jacobi1s_k
//   [4M, 8M)       Vfull  (64 x 128x128 f32)   -- dead after pmat_k
//   [8M, 8M+32K)   normg  (64 x 128 f32)       -- dead after pmat_k
//   [12M, 16M)     P      (64 x 128x128 f32)
// total requirement: 16 MB of d_ws.

#define NM 64
#define SEQ 2048
#define DD 128
#define RR 64
#define NSWEEP 7

#define OFF_VFULL (4194304ULL)
#define OFF_NORM  (8388608ULL)
#define OFF_P     (12582912ULL)

__device__ __forceinline__ float dot4(float4 a, float4 b) {
  // fmaf-explicit: bitwise identical in both redundant-compute roles
  // (operand swap inside fmaf's multiply commutes exactly).
  return fmaf(a.x, b.x, fmaf(a.y, b.y, fmaf(a.z, b.z, a.w * b.w)));
}
__device__ __forceinline__ float4 comb(float a, float4 x, float b, float4 y) {
  float4 r;
  r.x = fmaf(a, x.x, b * y.x);
  r.y = fmaf(a, x.y, b * y.y);
  r.z = fmaf(a, x.z, b * y.z);
  r.w = fmaf(a, x.w, b * y.w);
  return r;
}

// DPP butterfly add over aligned 16-lane groups (VALU pipe, DS pipe stays
// free). 0xB1=quad xor1, 0x4E=quad xor2, 0x141=row_half_mirror, 0x140=row_mirror.
template <int CTRL>
__device__ __forceinline__ float dpp_add(float x) {
  int y = __builtin_amdgcn_update_dpp(0, __float_as_int(x), CTRL, 0xf, 0xf, true);
  return x + __int_as_float(y);
}
__device__ __forceinline__ float red16(float x) {
  x = dpp_add<0xB1>(x);
  x = dpp_add<0x4E>(x);
  x = dpp_add<0x141>(x);
  x = dpp_add<0x140>(x);
  return x;
}

// ---------------- K1: Gram G[m] = X[m]^T X[m] ----------------
__global__ __launch_bounds__(256) void gram_k(const float* __restrict__ X,
                                              float* __restrict__ G) {
  const int m = blockIdx.y;
  const int r0 = blockIdx.x * 32;  // G row tile (== X column tile)
  const int tid = threadIdx.x;
  __shared__ __align__(16) float Xs[64][128];  // 32 KB
  const float* Xm = X + (size_t)m * SEQ * DD;
  const int ti = tid >> 5;  // 0..7  -> G rows r0+4ti..+3
  const int tj = tid & 31;  // 0..31 -> G cols 4tj..+3
  float acc[4][4];
#pragma unroll
  for (int a = 0; a < 4; ++a)
#pragma unroll
    for (int b = 0; b < 4; ++b) acc[a][b] = 0.f;

  for (int s0 = 0; s0 < SEQ; s0 += 64) {
    __syncthreads();
    for (int t = tid; t < 2048; t += 256) {  // 64 rows x 32 float4
      int s = t >> 5, c4 = t & 31;
      *(float4*)&Xs[s][c4 * 4] =
          *(const float4*)&Xm[(size_t)(s0 + s) * DD + c4 * 4];
    }
    __syncthreads();
#pragma unroll 4
    for (int s = 0; s < 64; ++s) {
      float4 av = *(const float4*)&Xs[s][r0 + 4 * ti];
      float4 bv = *(const float4*)&Xs[s][4 * tj];
      acc[0][0] += av.x * bv.x; acc[0][1] += av.x * bv.y;
      acc[0][2] += av.x * bv.z; acc[0][3] += av.x * bv.w;
      acc[1][0] += av.y * bv.x; acc[1][1] += av.y * bv.y;
      acc[1][2] += av.y * bv.z; acc[1][3] += av.y * bv.w;
      acc[2][0] += av.z * bv.x; acc[2][1] += av.z * bv.y;
      acc[2][2] += av.z * bv.z; acc[2][3] += av.z * bv.w;
      acc[3][0] += av.w * bv.x; acc[3][1] += av.w * bv.y;
      acc[3][2] += av.w * bv.z; acc[3][3] += av.w * bv.w;
    }
  }
  float* Gm = G + (size_t)m * DD * DD;
#pragma unroll
  for (int a = 0; a < 4; ++a) {
    float4 v = make_float4(acc[a][0], acc[a][1], acc[a][2], acc[a][3]);
    *(float4*)&Gm[(size_t)(r0 + 4 * ti + a) * DD + 4 * tj] = v;
  }
}

// ---------------- K2: register-resident brick-wall one-sided Jacobi --------
// 1024 threads = 64 groups x 16 lanes; group g owns slots (2g, 2g+1) as
// register columns L, R (2 float4/lane each) with carried squared norms.
// Even step: rotate (L,R) in registers, swap (brick-wall always-swap).
// Odd step: pairs (2g+1, 2g+2) span groups: both neighbors exchange the
// boundary columns through LDS and redundantly compute the same rotation
// (bit-identical by construction), each keeping its own slot's output.
// Coverage: odd-even transposition meets all 8128 column pairs per 128 steps.
__global__ __launch_bounds__(1024) void jacobi1s_k(const float* __restrict__ G,
                                                   float* __restrict__ Vfull,
                                                   float* __restrict__ normg) {
  const int m = blockIdx.x;
  const int tid = threadIdx.x;
  const int g = tid >> 4;  // group 0..63
  const int l = tid & 15;  // lane in group
  __shared__ __align__(16) float4 sbufR[63 * 32];  // writer g (0..62)
  __shared__ __align__(16) float4 sbufL[63 * 32];  // writer g (1..63) at g-1
  __shared__ float nRb[63], nLb[63];               // total 65,024 B

  const float4* Gm4 = (const float4*)(G + (size_t)m * DD * DD);
  // G symmetric: column j == row j -> transpose-free load.
  float4 L0 = Gm4[(2 * g) * 32 + l];
  float4 L1 = Gm4[(2 * g) * 32 + 16 + l];
  float4 R0 = Gm4[(2 * g + 1) * 32 + l];
  float4 R1 = Gm4[(2 * g + 1) * 32 + 16 + l];
  float nL = red16(dot4(L0, L0) + dot4(L1, L1));
  float nR = red16(dot4(R0, R0) + dot4(R1, R1));

  for (int s2 = 0; s2 < NSWEEP * 64; ++s2) {
    // ---- even step: local pair (2g, 2g+1) = (p=L, q=R); outputs swap ----
    {
      float apq = red16(dot4(L0, R0) + dot4(L1, R1));
      float app = nL, aqq = nR;
      if (apq * apq > 1e-9f * app * aqq) {
        float tau = (aqq - app) / (2.f * apq);
        float tv = 1.f / (fabsf(tau) + sqrtf(1.f + tau * tau));
        tv = tau < 0.f ? -tv : tv;
        float c = 1.f / sqrtf(1.f + tv * tv);
        float s = tv * c;
        float4 p0 = comb(c, L0, -s, R0), p1 = comb(c, L1, -s, R1);
        float4 q0 = comb(s, L0, c, R0), q1 = comb(s, L1, c, R1);
        L0 = q0; L1 = q1; R0 = p0; R1 = p1;  // q'->slot 2g, p'->slot 2g+1
        nL = aqq + tv * apq; nR = app - tv * apq;
      } else {
        float4 t0 = L0, t1 = L1; L0 = R0; L1 = R1; R0 = t0; R1 = t1;
        float tn = nL; nL = nR; nR = tn;
      }
    }
    // ---- odd step: pairs (2g+1, 2g+2); boundary exchange via LDS ----
    if (g < 63) { sbufR[g * 32 + l] = R0; sbufR[g * 32 + 16 + l] = R1; }
    if (g > 0)  { sbufL[(g - 1) * 32 + l] = L0; sbufL[(g - 1) * 32 + 16 + l] = L1; }
    if (l == 0) {
      if (g < 63) nRb[g] = nR;
      if (g > 0) nLb[g - 1] = nL;
    }
    __syncthreads();
    if (g < 63) {  // role-R: p = my R (slot 2g+1), q = right neighbor's L
      float4 q0 = sbufL[g * 32 + l], q1 = sbufL[g * 32 + 16 + l];
      float app = nR, aqq = nLb[g];
      float apq = red16(dot4(R0, q0) + dot4(R1, q1));
      if (apq * apq > 1e-9f * app * aqq) {
        float tau = (aqq - app) / (2.f * apq);
        float tv = 1.f / (fabsf(tau) + sqrtf(1.f + tau * tau));
        tv = tau < 0.f ? -tv : tv;
        float c = 1.f / sqrtf(1.f + tv * tv);
        float s = tv * c;
        R0 = comb(s, R0, c, q0); R1 = comb(s, R1, c, q1);  // keep q'
        nR = aqq + tv * apq;
      } else {
        R0 = q0; R1 = q1; nR = aqq;  // identity rotation still swaps
      }
    }
    if (g > 0) {  // role-L: p = left neighbor's R, q = my L (slot 2g)
      float4 p0 = sbufR[(g - 1) * 32 + l], p1 = sbufR[(g - 1) * 32 + 16 + l];
      float app = nRb[g - 1], aqq = nL;
      float apq = red16(dot4(p0, L0) + dot4(p1, L1));
      if (apq * apq > 1e-9f * app * aqq) {
        float tau = (aqq - app) / (2.f * apq);
        float tv = 1.f / (fabsf(tau) + sqrtf(1.f + tau * tau));
        tv = tau < 0.f ? -tv : tv;
        float c = 1.f / sqrtf(1.f + tv * tv);
        float s = tv * c;
        L0 = comb(c, p0, -s, L0); L1 = comb(c, p1, -s, L1);  // keep p'
        nL = app - tv * apq;
      } else {
        L0 = p0; L1 = p1; nL = app;
      }
    }
    __syncthreads();  // guards this step's buffer reads vs next step's writes
  }

  // Exact norms for normalization (carried norms only steer rotations).
  float nLe = red16(dot4(L0, L0) + dot4(L1, L1));
  float nRe = red16(dot4(R0, R0) + dot4(R1, R1));
  float4* V4 = (float4*)(Vfull + (size_t)m * DD * DD);
  V4[(2 * g) * 32 + l] = L0;      V4[(2 * g) * 32 + 16 + l] = L1;
  V4[(2 * g + 1) * 32 + l] = R0;  V4[(2 * g + 1) * 32 + 16 + l] = R1;
  if (l == 0) {
    normg[m * DD + 2 * g] = nLe;
    normg[m * DD + 2 * g + 1] = nRe;
  }
}

// ---------------- K3: P = sum_{top64} v v^T / |v|^2  (128x128) -------------
// Fused rank-select + normalize + Gram. 4 blocks/matrix (32 P-rows each).
__global__ __launch_bounds__(256) void pmat_k(const float* __restrict__ Vfull,
                                              const float* __restrict__ normg,
                                              float* __restrict__ P) {
  const int m = blockIdx.y;
  const int i0 = blockIdx.x * 32;
  const int t = threadIdx.x;
  __shared__ float n[DD];
  __shared__ int inv[RR];
  __shared__ float scl[RR];
  __shared__ __align__(16) float Vs[RR][132];  // scaled rows, 33.8 KB

  if (t < DD) n[t] = normg[m * DD + t];
  __syncthreads();
  if (t < DD) {
    float nt = n[t];
    int rk = 0;
    for (int k = 0; k < DD; ++k) {
      float nk = n[k];
      rk += ((nk > nt) || (nk == nt && k < t)) ? 1 : 0;
    }
    if (rk < RR) { inv[rk] = t; scl[rk] = 1.f / sqrtf(nt); }
  }
  __syncthreads();
  const float4* V4 = (const float4*)(Vfull + (size_t)m * DD * DD);
  for (int idx = t; idx < RR * 32; idx += 256) {
    int r = idx >> 5, c4 = idx & 31;
    float4 v = V4[inv[r] * 32 + c4];
    float sc = scl[r];
    *(float4*)&Vs[r][4 * c4] = make_float4(v.x * sc, v.y * sc, v.z * sc, v.w * sc);
  }
  __syncthreads();
  const int ti = t >> 5;  // 0..7 -> P rows i0+4ti..+3
  const int tj = t & 31;  // cols 4tj..+3
  float acc[4][4] = {{0.f,0.f,0.f,0.f},{0.f,0.f,0.f,0.f},
                     {0.f,0.f,0.f,0.f},{0.f,0.f,0.f,0.f}};
#pragma unroll 4
  for (int r = 0; r < RR; ++r) {
    float4 av = *(float4*)&Vs[r][i0 + 4 * ti];
    float4 bv = *(float4*)&Vs[r][4 * tj];
    acc[0][0] += av.x * bv.x; acc[0][1] += av.x * bv.y;
    acc[0][2] += av.x * bv.z; acc[0][3] += av.x * bv.w;
    acc[1][0] += av.y * bv.x; acc[1][1] += av.y * bv.y;
    acc[1][2] += av.y * bv.z; acc[1][3] += av.y * bv.w;
    acc[2][0] += av.z * bv.x; acc[2][1] += av.z * bv.y;
    acc[2][2] += av.z * bv.z; acc[2][3] += av.z * bv.w;
    acc[3][0] += av.w * bv.x; acc[3][1] += av.w * bv.y;
    acc[3][2] += av.w * bv.z; acc[3][3] += av.w * bv.w;
  }
  float* Pm = P + (size_t)m * DD * DD;
#pragma unroll
  for (int a = 0; a < 4; ++a) {
    float4 v = make_float4(acc[a][0], acc[a][1], acc[a][2], acc[a][3]);
    *(float4*)&Pm[(size_t)(i0 + 4 * ti + a) * DD + 4 * tj] = v;
  }
}

// ---------------- K4: out = X @ P  (2048x128 per matrix) -------------------
// 64-row x 64-col tiles, K=128 in two 64-chunks (LDS 34.8 KB -> 3-4 blk/CU).
// X tile staged TRANSPOSED so the inner loop is b128+b128 per 16 FMA.
__global__ __launch_bounds__(256) void recon_k(const float* __restrict__ X,
                                               const float* __restrict__ P,
                                               float* __restrict__ out) {
  const int m = blockIdx.y;
  const int rt = blockIdx.x >> 1, jt = blockIdx.x & 1;
  const int s0 = rt * 64, j0 = jt * 64;
  const int t = threadIdx.x;
  __shared__ __align__(16) float Ps[64 * 68];   // [k][j-local], 17.4 KB
  __shared__ __align__(16) float XsT[64 * 68];  // [k][row-local], 17.4 KB
  const float4* P4 = (const float4*)(P + (size_t)m * DD * DD);
  const float4* Xm4 = (const float4*)(X + ((size_t)m * SEQ + s0) * DD);
  const int ti = t >> 4;  // 0..15 -> rows 4ti..+3
  const int tj = t & 15;  // 0..15 -> cols j0+4tj..+3
  float acc[4][4] = {{0.f,0.f,0.f,0.f},{0.f,0.f,0.f,0.f},
                     {0.f,0.f,0.f,0.f},{0.f,0.f,0.f,0.f}};
#pragma unroll
  for (int kc = 0; kc < 2; ++kc) {
    __syncthreads();
    for (int idx = t; idx < 1024; idx += 256) {  // Ps: 64 k x 16 float4
      int k = idx >> 4, c4 = idx & 15;
      *(float4*)&Ps[k * 68 + 4 * c4] = P4[(kc * 64 + k) * 32 + jt * 16 + c4];
    }
    for (int idx = t; idx < 1024; idx += 256) {  // XsT: 64 rows x 16 float4
      int r = idx >> 4, c4 = idx & 15;
      float4 v = Xm4[r * 32 + kc * 16 + c4];
      XsT[(4 * c4 + 0) * 68 + r] = v.x;
      XsT[(4 * c4 + 1) * 68 + r] = v.y;
      XsT[(4 * c4 + 2) * 68 + r] = v.z;
      XsT[(4 * c4 + 3) * 68 + r] = v.w;
    }
    __syncthreads();
#pragma unroll 4
    for (int k = 0; k < 64; ++k) {
      float4 av = *(float4*)&XsT[k * 68 + 4 * ti];
      float4 bv = *(float4*)&Ps[k * 68 + 4 * tj];
      acc[0][0] += av.x * bv.x; acc[0][1] += av.x * bv.y;
      acc[0][2] += av.x * bv.z; acc[0][3] += av.x * bv.w;
      acc[1][0] += av.y * bv.x; acc[1][1] += av.y * bv.y;
      acc[1][2] += av.y * bv.z; acc[1][3] += av.y * bv.w;
      acc[2][0] += av.z * bv.x; acc[2][1] += av.z * bv.y;
      acc[2][2] += av.z * bv.z; acc[2][3] += av.z * bv.w;
      acc[3][0] += av.w * bv.x; acc[3][1] += av.w * bv.y;
      acc[3][2] += av.w * bv.z; acc[3][3] += av.w * bv.w;
    }
  }
  float* Om = out + ((size_t)m * SEQ + s0) * DD;
#pragma unroll
  for (int a = 0; a < 4; ++a) {
    float4 v = make_float4(acc[a][0], acc[a][1], acc[a][2], acc[a][3]);
    *(float4*)&Om[(size_t)(4 * ti + a) * DD + j0 + 4 * tj] = v;
  }
}

extern "C" void kernel_launch(void* const* d_in, const int* in_sizes, int n_in,
                              void* d_out, int out_size, void* d_ws, size_t ws_size,
                              hipStream_t stream) {
  (void)in_sizes; (void)n_in; (void)out_size; (void)ws_size;
  const float* X = (const float*)d_in[0];  // rank (d_in[1]) is fixed at 64
  float* out = (float*)d_out;
  char* ws = (char*)d_ws;
  float* G = (float*)ws;
  float* Vfull = (float*)(ws + OFF_VFULL);
  float* normg = (float*)(ws + OFF_NORM);
  float* P = (float*)(ws + OFF_P);

  gram_k<<<dim3(4, NM), 256, 0, stream>>>(X, G);
  jacobi1s_k<<<NM, 1024, 0, stream>>>(G, Vfull, normg);
  pmat_k<<<dim3(4, NM), 256, 0, stream>>>(Vfull, normg, P);
  recon_k<<<dim3(64, NM), 256, 0, stream>>>(X, P, out);
}